// Round 9
// baseline (7576.632 us; speedup 1.0000x reference)
//
#include <hip/hip_runtime.h>
#include <math.h>

#define TT 32
#define DD 64
#define NN 1024
#define VV 64
#define RR 4
#define HH 512

typedef unsigned int uint_t;
typedef unsigned short ushort_t;

__device__ __forceinline__ float sigf(float x) { return 1.0f / (1.0f + __expf(-x)); }
__device__ __forceinline__ float splus(float x) {
  return (x > 0.f) ? (x + log1pf(__expf(-x))) : log1pf(__expf(x));
}
__device__ __forceinline__ float dot4f(float4 a, float4 b) {
  return a.x * b.x + a.y * b.y + a.z * b.z + a.w * b.w;
}
__device__ __forceinline__ ushort_t bfr(float f) {
  uint_t u = __float_as_uint(f);
  return (ushort_t)((u + 0x7fffu + ((u >> 16) & 1u)) >> 16);
}
__device__ __forceinline__ float bflo(uint_t u) { return __uint_as_float(u << 16); }
__device__ __forceinline__ float bfhi(uint_t u) { return __uint_as_float(u & 0xffff0000u); }
__device__ __forceinline__ uint_t packbf(float a, float b) {
  return (uint_t)bfr(a) | ((uint_t)bfr(b) << 16);
}

// ============ pre-kernels (every launch; deterministic) ============
// Combined gates+out weight, bf16 pairs, row-reordered:
// rows 0..2047: row = h*4+g  <- [W_ih[g*512+h] (k 0..319) | W_hh[g*512+h] (k 320..831)]
// rows 2048..2111: out row j <- [0 (k<64) | out_W[j][512..767] (k 64..319) | out_W[j][0..511] (k>=320)]
__global__ void build_gw(const float* __restrict__ W_ih, const float* __restrict__ W_hh,
                         const float* __restrict__ out_W, uint_t* __restrict__ W2g) {
  int idx = blockIdx.x * 256 + threadIdx.x;           // 2112*416
  if (idx >= 2112 * 416) return;
  int r = idx / 416, kp = idx - r * 416;
  float v[2];
  #pragma unroll
  for (int q = 0; q < 2; ++q) {
    int k = 2 * kp + q;
    float f;
    if (r < 2048) {
      int h = r >> 2, g = r & 3, row = g * 512 + h;
      f = (k < 320) ? W_ih[(size_t)row * 320 + k] : W_hh[(size_t)row * 512 + (k - 320)];
    } else {
      int j = r - 2048;
      if (k < 64) f = 0.f;
      else if (k < 320) f = out_W[(size_t)j * 768 + 512 + (k - 64)];
      else f = out_W[(size_t)j * 768 + (k - 320)];
    }
    v[q] = f;
  }
  W2g[idx] = packbf(v[0], v[1]);
}
// Head weights: rows 0..279 = read_W, 280..1071 = write_W; K=512 (bf16 pairs).
__global__ void build_hw(const float* __restrict__ read_W, const float* __restrict__ write_W,
                         uint_t* __restrict__ W2h) {
  int idx = blockIdx.x * 256 + threadIdx.x;           // 1072*256
  if (idx >= 1072 * 256) return;
  int r = idx >> 8, kp = idx & 255;
  const float* src = (r < 280) ? (read_W + (size_t)r * 512) : (write_W + (size_t)(r - 280) * 512);
  W2h[idx] = packbf(src[2 * kp], src[2 * kp + 1]);
}
__global__ void bias_kernel(const float* __restrict__ bi, const float* __restrict__ bh,
                            float* __restrict__ o) {
  int i = blockIdx.x * 256 + threadIdx.x;
  if (i < 2048) o[i] = bi[i] + bh[i];
}
// init: mem bf16, A2 (x0, read_init, h_bias slot0), c, ws zero. grid 64 x 1024.
__global__ void k0_init(const float* __restrict__ x, const float* __restrict__ mem_bias,
                        const float* __restrict__ h_bias, const float* __restrict__ c_bias,
                        const float* __restrict__ read_init,
                        ushort_t* __restrict__ g_mem, uint_t* __restrict__ A2,
                        float* __restrict__ g_c, float* __restrict__ g_ws) {
  const int b = blockIdx.x, tid = threadIdx.x;
  { // mem row tid -> bf16
    const float4* src = (const float4*)(mem_bias + (size_t)tid * VV);
    uint4* dst = (uint4*)(g_mem + (size_t)b * (NN * VV) + (size_t)tid * VV);
    #pragma unroll
    for (int p = 0; p < 8; ++p) {
      float4 va = src[2 * p], vb = src[2 * p + 1];
      uint4 o;
      o.x = packbf(va.x, va.y); o.y = packbf(va.z, va.w);
      o.z = packbf(vb.x, vb.y); o.w = packbf(vb.z, vb.w);
      dst[p] = o;
    }
  }
  if (tid < 416) {
    float v0, v1;
    if (tid < 32)      { v0 = x[((size_t)b * TT) * DD + 2 * tid]; v1 = x[((size_t)b * TT) * DD + 2 * tid + 1]; }
    else if (tid < 160){ int e = 2 * (tid - 32); v0 = read_init[e]; v1 = read_init[e + 1]; }
    else               { int e = 2 * (tid - 160); v0 = h_bias[e]; v1 = h_bias[e + 1]; }
    A2[(size_t)tid * 64 + b] = packbf(v0, v1);
  }
  if (tid < 512) g_c[(size_t)tid * 64 + b] = c_bias[tid];
  for (int i = tid; i < 8192; i += 1024) g_ws[(size_t)b * 8192 + i] = 0.f;
}

// ============ K1: gates GEMM + LSTM + out(t-1) rows ============
__global__ __launch_bounds__(512) void k1_gates(
    int t, int nGate, int par,
    const uint_t* __restrict__ W2g, const float* __restrict__ gbias,
    uint_t* __restrict__ A2, float* __restrict__ g_c,
    const float* __restrict__ out_b, float* __restrict__ out) {
  const int blk = blockIdx.x, tid = threadIdx.x;
  const int lane = tid & 63, u = tid >> 6;
  const bool isGate = (blk < nGate);
  if (!isGate && t == 0) return;
  __shared__ uint_t s_tile[52 * 64];
  __shared__ float s_h[8 * 64];
  float acc0 = 0.f, acc1 = 0.f, acc2 = 0.f, acc3 = 0.f;
  const int hglob = blk * 8 + u;                       // gate block
  const int orow = 2048 + (blk - nGate) * 8 + u;       // out block
  const size_t wbase = isGate ? (size_t)(hglob * 4) * 416 : (size_t)orow * 416;

  for (int c = 0; c < 8; ++c) {
    for (int i = tid; i < 52 * 64; i += 512) {
      int kk = i >> 6, bb = i & 63;
      int kpg = c * 52 + kk;
      int phys = (kpg < 160) ? kpg : kpg + 256 * par;
      s_tile[i] = A2[(size_t)phys * 64 + bb];
    }
    __syncthreads();
    const uint_t* wrow = W2g + wbase + c * 52;
    if (isGate) {
      #pragma unroll 4
      for (int kk = 0; kk < 52; ++kk) {
        uint_t ua = s_tile[kk * 64 + lane];
        float a0 = bflo(ua), a1 = bfhi(ua);
        uint_t w0 = wrow[kk], w1 = wrow[416 + kk], w2 = wrow[832 + kk], w3 = wrow[1248 + kk];
        acc0 += bflo(w0) * a0 + bfhi(w0) * a1;
        acc1 += bflo(w1) * a0 + bfhi(w1) * a1;
        acc2 += bflo(w2) * a0 + bfhi(w2) * a1;
        acc3 += bflo(w3) * a0 + bfhi(w3) * a1;
      }
    } else {
      #pragma unroll 4
      for (int kk = 0; kk < 52; ++kk) {
        uint_t ua = s_tile[kk * 64 + lane];
        uint_t w0 = wrow[kk];
        acc0 += bflo(w0) * bflo(ua) + bfhi(w0) * bfhi(ua);
      }
    }
    __syncthreads();
  }

  if (isGate) {
    float gi = acc0 + gbias[hglob];
    float gf = acc1 + gbias[512 + hglob];
    float gg = acc2 + gbias[1024 + hglob];
    float go = acc3 + gbias[1536 + hglob];
    float c0 = g_c[(size_t)hglob * 64 + lane];
    float cn = sigf(gf) * c0 + sigf(gi) * tanhf(gg);
    float hn = sigf(go) * tanhf(cn);
    g_c[(size_t)hglob * 64 + lane] = cn;
    s_h[u * 64 + lane] = hn;
    __syncthreads();
    if (tid < 256) {
      int q = tid >> 6;
      float h0 = s_h[(2 * q) * 64 + lane], h1 = s_h[(2 * q + 1) * 64 + lane];
      int kp = 160 + 256 * (par ^ 1) + blk * 4 + q;
      A2[(size_t)kp * 64 + lane] = packbf(h0, h1);
    }
  } else {
    int j = orow - 2048;
    out[((size_t)lane * TT + (t - 1)) * DD + j] = sigf(acc0 + out_b[j]);
  }
}

// ============ K2: head projections GEMM ============
__global__ __launch_bounds__(512) void k2_heads(
    int wslot, const uint_t* __restrict__ W2h,
    const float* __restrict__ read_b, const float* __restrict__ write_b,
    const uint_t* __restrict__ A2, float* __restrict__ g_headp) {
  const int blk = blockIdx.x, tid = threadIdx.x;
  const int lane = tid & 63, u = tid >> 6;
  const int r = blk * 8 + u;
  __shared__ uint_t s_tile[64 * 64];
  __shared__ float s_tr[8 * 65];
  const int hbase = 160 + 256 * wslot;
  float acc = 0.f;
  const uint_t* wrow = W2h + (size_t)r * 256;
  for (int c = 0; c < 4; ++c) {
    for (int i = tid; i < 64 * 64; i += 512) {
      int kk = i >> 6, bb = i & 63;
      s_tile[i] = A2[(size_t)(hbase + c * 64 + kk) * 64 + bb];
    }
    __syncthreads();
    #pragma unroll 4
    for (int kk = 0; kk < 64; ++kk) {
      uint_t ua = s_tile[kk * 64 + lane];
      uint_t w = wrow[c * 64 + kk];
      acc += bflo(w) * bflo(ua) + bfhi(w) * bfhi(ua);
    }
    __syncthreads();
  }
  acc += (r < 280) ? read_b[r] : write_b[r - 280];
  s_tr[u * 65 + lane] = acc;
  __syncthreads();
  if (tid < 128) {
    int bb = tid & 63, half = tid >> 6;
    float4 v;
    v.x = s_tr[(half * 4 + 0) * 65 + bb];
    v.y = s_tr[(half * 4 + 1) * 65 + bb];
    v.z = s_tr[(half * 4 + 2) * 65 + bb];
    v.w = s_tr[(half * 4 + 3) * 65 + bb];
    *(float4*)(g_headp + (size_t)bb * 1088 + blk * 8 + half * 4) = v;
  }
}

// ============ K3: per-batch memory phase (dual softmax + fused einsum/erase) ============
__global__ __launch_bounds__(1024) void k3_mem(
    int t, const float* __restrict__ x, const float* __restrict__ g_headp,
    ushort_t* __restrict__ g_mem, uint_t* __restrict__ A2,
    float* __restrict__ g_ws) {
  const int b = blockIdx.x, tid = threadIdx.x;
  const int lane = tid & 63, wave = tid >> 6;
  __shared__ alignas(16) float s_scr[2048];   // [0..1023] wR final; [1024..2047] wgR
  __shared__ alignas(16) float s_wg2[1024];   // wgW, then wW final
  __shared__ alignas(16) float s_part[1024];  // einsum partials (wave x col)
  __shared__ alignas(16) float s_reads[RR * VV];
  __shared__ alignas(16) float s_or[72];
  __shared__ alignas(16) float s_ow[200];
  __shared__ alignas(16) float s_e[VV];
  __shared__ alignas(16) float s_a[VV];
  __shared__ float s_redR[16];
  __shared__ float s_redW[16];
  ushort_t* membf = g_mem + (size_t)b * (NN * VV);
  uint_t* m32 = (uint_t*)membf;
  const float* hp = g_headp + (size_t)b * 1088;

  for (int hd = 0; hd < RR; ++hd) {
    if (tid < 70) s_or[tid] = hp[hd * 70 + tid];
    else if (tid >= 128 && tid < 326) s_ow[tid - 128] = hp[280 + hd * 198 + (tid - 128)];
    __syncthreads();
    if (tid < VV) { s_e[tid] = sigf(s_ow[70 + tid]); s_a[tid] = s_ow[134 + tid]; }

    float wprevR = g_ws[(size_t)(b * 8 + 2 * hd) * 1024 + tid];
    float wprevW = g_ws[(size_t)(b * 8 + 2 * hd + 1) * 1024 + tid];

    // ---- dot pass: row tid (uint4 loads), dual keys, inline |row|^2 ----
    float dotR = 0.f, dotW = 0.f, kkR = 0.f, kkW = 0.f, nrm2 = 0.f;
    {
      const uint4* rowp = (const uint4*)(membf + (size_t)tid * VV);
      const float4* orf = (const float4*)s_or;
      const float4* owf = (const float4*)s_ow;
      #pragma unroll
      for (int p = 0; p < 8; ++p) {
        uint4 m = rowp[p];
        float4 ka = orf[2 * p], kb = orf[2 * p + 1];
        float4 wa = owf[2 * p], wb = owf[2 * p + 1];
        kkR += dot4f(ka, ka) + dot4f(kb, kb);
        kkW += dot4f(wa, wa) + dot4f(wb, wb);
        float m0 = bflo(m.x), m1 = bfhi(m.x), m2 = bflo(m.y), m3 = bfhi(m.y);
        float m4 = bflo(m.z), m5 = bfhi(m.z), m6 = bflo(m.w), m7 = bfhi(m.w);
        nrm2 += m0 * m0 + m1 * m1 + m2 * m2 + m3 * m3 + m4 * m4 + m5 * m5 + m6 * m6 + m7 * m7;
        dotR += m0 * ka.x + m1 * ka.y + m2 * ka.z + m3 * ka.w +
                m4 * kb.x + m5 * kb.y + m6 * kb.z + m7 * kb.w;
        dotW += m0 * wa.x + m1 * wa.y + m2 * wa.z + m3 * wa.w +
                m4 * wb.x + m5 * wb.y + m6 * wb.z + m7 * wb.w;
      }
    }
    float na = fmaxf(sqrtf(nrm2), 1e-8f);

    // ---- dual softmax chain (shared syncs) ----
    float nbR = fmaxf(sqrtf(kkR), 1e-8f), nbW = fmaxf(sqrtf(kkW), 1e-8f);
    float betaR = splus(s_or[64]), betaW = splus(s_ow[64]);
    float gR = sigf(s_or[65]), gW = sigf(s_ow[65]);
    float r0 = s_or[66], r1 = s_or[67], r2 = s_or[68];
    float q0 = s_ow[66], q1 = s_ow[67], q2 = s_ow[68];
    float mxR = fmaxf(r0, fmaxf(r1, r2)), mxW = fmaxf(q0, fmaxf(q1, q2));
    float eR0 = __expf(r0 - mxR), eR1 = __expf(r1 - mxR), eR2 = __expf(r2 - mxR);
    float eW0 = __expf(q0 - mxW), eW1 = __expf(q1 - mxW), eW2 = __expf(q2 - mxW);
    float siR = 1.0f / (eR0 + eR1 + eR2), siW = 1.0f / (eW0 + eW1 + eW2);
    float gamR = 1.0f + splus(s_or[69]), gamW = 1.0f + splus(s_ow[69]);
    float eeR = __expf(betaR * dotR / (na * nbR));   // |z|<=beta: no max-sub
    float eeW = __expf(betaW * dotW / (na * nbW));
    float vR = eeR, vW = eeW;
    #pragma unroll
    for (int o = 32; o; o >>= 1) { vR += __shfl_xor(vR, o); vW += __shfl_xor(vW, o); }
    if (lane == 0) { s_redR[wave] = vR; s_redW[wave] = vW; }
    __syncthreads();                                  // S1
    float SR = 0.f, SW = 0.f;
    #pragma unroll
    for (int w = 0; w < 16; ++w) { SR += s_redR[w]; SW += s_redW[w]; }
    float wgR = gR * (eeR / SR) + (1.0f - gR) * wprevR;
    float wgW = gW * (eeW / SW) + (1.0f - gW) * wprevW;
    s_scr[1024 + tid] = wgR;
    s_wg2[tid] = wgW;
    __syncthreads();                                  // S2
    int tm = (tid + 1023) & 1023, tp = (tid + 1) & 1023;
    float wsnR = (eR0 * siR) * s_scr[1024 + tm] + (eR1 * siR) * s_scr[1024 + tid] +
                 (eR2 * siR) * s_scr[1024 + tp];
    float wsnW = (eW0 * siW) * s_wg2[tm] + (eW1 * siW) * s_wg2[tid] +
                 (eW2 * siW) * s_wg2[tp];
    float wpR = __expf(gamR * __logf(wsnR));
    float wpW = __expf(gamW * __logf(wsnW));
    vR = wpR; vW = wpW;
    #pragma unroll
    for (int o = 32; o; o >>= 1) { vR += __shfl_xor(vR, o); vW += __shfl_xor(vW, o); }
    if (lane == 0) { s_redR[wave] = vR; s_redW[wave] = vW; }
    __syncthreads();                                  // S3
    float ZR = 0.f, ZW = 0.f;
    #pragma unroll
    for (int w = 0; w < 16; ++w) { ZR += s_redR[w]; ZW += s_redW[w]; }
    float wRf = wpR / (ZR + 1e-16f);
    float wWf = wpW / (ZW + 1e-16f);
    s_scr[tid] = wRf;
    g_ws[(size_t)(b * 8 + 2 * hd) * 1024 + tid] = wRf;
    g_ws[(size_t)(b * 8 + 2 * hd + 1) * 1024 + tid] = wWf;
    __syncthreads();                                  // S4 (wgW consumed; safe to overwrite)
    s_wg2[tid] = wWf;
    __syncthreads();                                  // S5: wR/wW visible

    // ---- fused einsum + erase: wave = 64 rows, lane = 2 columns (dense 256B/instr) ----
    {
      const int cp = lane & 31, rp = lane >> 5;
      const float e0 = s_e[2 * cp], e1 = s_e[2 * cp + 1];
      const float a0 = s_a[2 * cp], a1 = s_a[2 * cp + 1];
      const int base = wave * 64;
      float acc0 = 0.f, acc1 = 0.f;
      #pragma unroll 8
      for (int r = 0; r < 32; ++r) {
        int row = base + 2 * r + rp;
        uint_t uu = m32[row * 32 + cp];
        float wRn = s_scr[row];
        float wWn = s_wg2[row];
        float v0 = bflo(uu), v1 = bfhi(uu);
        acc0 += wRn * v0; acc1 += wRn * v1;
        float n0 = v0 * (1.f - wWn * e0) + wWn * a0;
        float n1 = v1 * (1.f - wWn * e1) + wWn * a1;
        m32[row * 32 + cp] = packbf(n0, n1);
      }
      acc0 += __shfl_xor(acc0, 32);
      acc1 += __shfl_xor(acc1, 32);
      if (rp == 0) *(float2*)(s_part + wave * 64 + 2 * cp) = make_float2(acc0, acc1);
    }
    __syncthreads();                                  // S6 (drains stores; next head's dot safe)
    if (tid < VV) {
      float s = 0.f;
      #pragma unroll
      for (int w2 = 0; w2 < 16; ++w2) s += s_part[w2 * 64 + tid];
      s_reads[hd * VV + tid] = s;
    }
    __syncthreads();
  } // hd

  // publish reads_t and x_{t+1} into A (bf16 pairs)
  if (tid < 128)
    A2[(size_t)(32 + tid) * 64 + b] = packbf(s_reads[2 * tid], s_reads[2 * tid + 1]);
  if (tid < 32 && t + 1 < TT) {
    float v0 = x[((size_t)b * TT + t + 1) * DD + 2 * tid];
    float v1 = x[((size_t)b * TT + t + 1) * DD + 2 * tid + 1];
    A2[(size_t)tid * 64 + b] = packbf(v0, v1);
  }
}

extern "C" void kernel_launch(void* const* d_in, const int* in_sizes, int n_in,
                              void* d_out, int out_size, void* d_ws, size_t ws_size,
                              hipStream_t stream) {
  char* ws = (char*)d_ws;
  ushort_t* g_mem = (ushort_t*)ws;                 // 8,388,608
  uint_t* g_A2    = (uint_t*)(ws + 8388608);       //   172,032
  float* g_c      = (float*)(ws + 8560640);        //   131,072
  float* g_ws     = (float*)(ws + 8691712);        // 2,097,152
  float* g_headp  = (float*)(ws + 10788864);       //   278,528
  uint_t* W2g     = (uint_t*)(ws + 11067392);      // 3,514,368
  uint_t* W2h     = (uint_t*)(ws + 14581760);      // 1,097,728
  float* gbias    = (float*)(ws + 15679488);       //     8,192   (~15.7 MB)

  const float* x        = (const float*)d_in[0];
  const float* mem_bias = (const float*)d_in[1];
  const float* h_bias   = (const float*)d_in[2];
  const float* c_bias   = (const float*)d_in[3];
  const float* W_ih     = (const float*)d_in[4];
  const float* W_hh     = (const float*)d_in[5];
  const float* b_ih     = (const float*)d_in[6];
  const float* b_hh     = (const float*)d_in[7];
  const float* read_W   = (const float*)d_in[8];
  const float* read_b   = (const float*)d_in[9];
  const float* write_W  = (const float*)d_in[10];
  const float* write_b  = (const float*)d_in[11];
  const float* read_init= (const float*)d_in[12];
  const float* out_W    = (const float*)d_in[13];
  const float* out_b    = (const float*)d_in[14];
  float* out = (float*)d_out;

  bias_kernel<<<8, 256, 0, stream>>>(b_ih, b_hh, gbias);
  build_gw<<<3432, 256, 0, stream>>>(W_ih, W_hh, out_W, W2g);
  build_hw<<<1072, 256, 0, stream>>>(read_W, write_W, W2h);
  k0_init<<<64, 1024, 0, stream>>>(x, mem_bias, h_bias, c_bias, read_init,
                                   g_mem, g_A2, g_c, g_ws);
  for (int t = 0; t < TT; ++t) {
    k1_gates<<<72, 512, 0, stream>>>(t, 64, t & 1, W2g, gbias, g_A2, g_c, out_b, out);
    k2_heads<<<134, 512, 0, stream>>>((t + 1) & 1, W2h, read_b, write_b, g_A2, g_headp);
    k3_mem<<<64, 1024, 0, stream>>>(t, x, g_headp, g_mem, g_A2, g_ws);
  }
  // final out row batch: out(t=31) from h_31 (slot 0) + reads_31
  k1_gates<<<8, 512, 0, stream>>>(TT, 0, 0, W2g, gbias, g_A2, g_c, out_b, out);
}

// Round 10
// 4947.088 us; speedup vs baseline: 1.5315x; 1.5315x over previous
//
#include <hip/hip_runtime.h>
#include <math.h>

#define TT 32
#define DD 64
#define NN 1024
#define VV 64
#define RR 4
#define HH 512

typedef unsigned int uint_t;
typedef unsigned short ushort_t;

__device__ __forceinline__ float sigf(float x) { return 1.0f / (1.0f + __expf(-x)); }
__device__ __forceinline__ float splus(float x) {
  return (x > 0.f) ? (x + log1pf(__expf(-x))) : log1pf(__expf(x));
}
__device__ __forceinline__ float dot4f(float4 a, float4 b) {
  return a.x * b.x + a.y * b.y + a.z * b.z + a.w * b.w;
}
__device__ __forceinline__ ushort_t bfr(float f) {
  uint_t u = __float_as_uint(f);
  return (ushort_t)((u + 0x7fffu + ((u >> 16) & 1u)) >> 16);
}
__device__ __forceinline__ float bflo(uint_t u) { return __uint_as_float(u << 16); }
__device__ __forceinline__ float bfhi(uint_t u) { return __uint_as_float(u & 0xffff0000u); }
__device__ __forceinline__ uint_t packbf(float a, float b) {
  return (uint_t)bfr(a) | ((uint_t)bfr(b) << 16);
}

// ============ pre-kernels (every launch; deterministic) ============
__global__ void build_gw(const float* __restrict__ W_ih, const float* __restrict__ W_hh,
                         const float* __restrict__ out_W, uint_t* __restrict__ W2g) {
  int idx = blockIdx.x * 256 + threadIdx.x;           // 2112*416
  if (idx >= 2112 * 416) return;
  int r = idx / 416, kp = idx - r * 416;
  float v[2];
  #pragma unroll
  for (int q = 0; q < 2; ++q) {
    int k = 2 * kp + q;
    float f;
    if (r < 2048) {
      int h = r >> 2, g = r & 3, row = g * 512 + h;
      f = (k < 320) ? W_ih[(size_t)row * 320 + k] : W_hh[(size_t)row * 512 + (k - 320)];
    } else {
      int j = r - 2048;
      if (k < 64) f = 0.f;
      else if (k < 320) f = out_W[(size_t)j * 768 + 512 + (k - 64)];
      else f = out_W[(size_t)j * 768 + (k - 320)];
    }
    v[q] = f;
  }
  W2g[idx] = packbf(v[0], v[1]);
}
__global__ void build_hw(const float* __restrict__ read_W, const float* __restrict__ write_W,
                         uint_t* __restrict__ W2h) {
  int idx = blockIdx.x * 256 + threadIdx.x;           // 1072*256
  if (idx >= 1072 * 256) return;
  int r = idx >> 8, kp = idx & 255;
  const float* src = (r < 280) ? (read_W + (size_t)r * 512) : (write_W + (size_t)(r - 280) * 512);
  W2h[idx] = packbf(src[2 * kp], src[2 * kp + 1]);
}
__global__ void bias_kernel(const float* __restrict__ bi, const float* __restrict__ bh,
                            float* __restrict__ o) {
  int i = blockIdx.x * 256 + threadIdx.x;
  if (i < 2048) o[i] = bi[i] + bh[i];
}
__global__ void k0_init(const float* __restrict__ x, const float* __restrict__ mem_bias,
                        const float* __restrict__ h_bias, const float* __restrict__ c_bias,
                        const float* __restrict__ read_init,
                        ushort_t* __restrict__ g_mem, uint_t* __restrict__ A2,
                        float* __restrict__ g_c, float* __restrict__ g_ws) {
  const int b = blockIdx.x, tid = threadIdx.x;
  { // mem row tid -> bf16
    const float4* src = (const float4*)(mem_bias + (size_t)tid * VV);
    uint4* dst = (uint4*)(g_mem + (size_t)b * (NN * VV) + (size_t)tid * VV);
    #pragma unroll
    for (int p = 0; p < 8; ++p) {
      float4 va = src[2 * p], vb = src[2 * p + 1];
      uint4 o;
      o.x = packbf(va.x, va.y); o.y = packbf(va.z, va.w);
      o.z = packbf(vb.x, vb.y); o.w = packbf(vb.z, vb.w);
      dst[p] = o;
    }
  }
  if (tid < 416) {
    float v0, v1;
    if (tid < 32)      { v0 = x[((size_t)b * TT) * DD + 2 * tid]; v1 = x[((size_t)b * TT) * DD + 2 * tid + 1]; }
    else if (tid < 160){ int e = 2 * (tid - 32); v0 = read_init[e]; v1 = read_init[e + 1]; }
    else               { int e = 2 * (tid - 160); v0 = h_bias[e]; v1 = h_bias[e + 1]; }
    A2[(size_t)tid * 64 + b] = packbf(v0, v1);
  }
  if (tid < 512) g_c[(size_t)tid * 64 + b] = c_bias[tid];
  for (int i = tid; i < 8192; i += 1024) g_ws[(size_t)b * 8192 + i] = 0.f;
}

// ============ K1: gates GEMM + LSTM + out(t-1) rows ============
__global__ __launch_bounds__(512) void k1_gates(
    int t, int nGate, int par,
    const uint_t* __restrict__ W2g, const float* __restrict__ gbias,
    uint_t* __restrict__ A2, float* __restrict__ g_c,
    const float* __restrict__ out_b, float* __restrict__ out) {
  const int blk = blockIdx.x, tid = threadIdx.x;
  const int lane = tid & 63, u = tid >> 6;
  const bool isGate = (blk < nGate);
  if (!isGate && t == 0) return;
  __shared__ uint_t s_tile[52 * 64];
  __shared__ float s_h[8 * 64];
  float acc0 = 0.f, acc1 = 0.f, acc2 = 0.f, acc3 = 0.f;
  const int hglob = blk * 8 + u;                       // gate block
  const int orow = 2048 + (blk - nGate) * 8 + u;       // out block
  const size_t wbase = isGate ? (size_t)(hglob * 4) * 416 : (size_t)orow * 416;

  for (int c = 0; c < 8; ++c) {
    for (int i = tid; i < 52 * 64; i += 512) {
      int kk = i >> 6, bb = i & 63;
      int kpg = c * 52 + kk;
      int phys = (kpg < 160) ? kpg : kpg + 256 * par;
      s_tile[i] = A2[(size_t)phys * 64 + bb];
    }
    __syncthreads();
    const uint_t* wrow = W2g + wbase + c * 52;
    if (isGate) {
      #pragma unroll 4
      for (int kk = 0; kk < 52; ++kk) {
        uint_t ua = s_tile[kk * 64 + lane];
        float a0 = bflo(ua), a1 = bfhi(ua);
        uint_t w0 = wrow[kk], w1 = wrow[416 + kk], w2 = wrow[832 + kk], w3 = wrow[1248 + kk];
        acc0 += bflo(w0) * a0 + bfhi(w0) * a1;
        acc1 += bflo(w1) * a0 + bfhi(w1) * a1;
        acc2 += bflo(w2) * a0 + bfhi(w2) * a1;
        acc3 += bflo(w3) * a0 + bfhi(w3) * a1;
      }
    } else {
      #pragma unroll 4
      for (int kk = 0; kk < 52; ++kk) {
        uint_t ua = s_tile[kk * 64 + lane];
        uint_t w0 = wrow[kk];
        acc0 += bflo(w0) * bflo(ua) + bfhi(w0) * bfhi(ua);
      }
    }
    __syncthreads();
  }

  if (isGate) {
    float gi = acc0 + gbias[hglob];
    float gf = acc1 + gbias[512 + hglob];
    float gg = acc2 + gbias[1024 + hglob];
    float go = acc3 + gbias[1536 + hglob];
    float c0 = g_c[(size_t)hglob * 64 + lane];
    float cn = sigf(gf) * c0 + sigf(gi) * tanhf(gg);
    float hn = sigf(go) * tanhf(cn);
    g_c[(size_t)hglob * 64 + lane] = cn;
    s_h[u * 64 + lane] = hn;
    __syncthreads();
    if (tid < 256) {
      int q = tid >> 6;
      float h0 = s_h[(2 * q) * 64 + lane], h1 = s_h[(2 * q + 1) * 64 + lane];
      int kp = 160 + 256 * (par ^ 1) + blk * 4 + q;
      A2[(size_t)kp * 64 + lane] = packbf(h0, h1);
    }
  } else {
    int j = orow - 2048;
    out[((size_t)lane * TT + (t - 1)) * DD + j] = sigf(acc0 + out_b[j]);
  }
}

// ============ K2: head projections GEMM ============
__global__ __launch_bounds__(512) void k2_heads(
    int wslot, const uint_t* __restrict__ W2h,
    const float* __restrict__ read_b, const float* __restrict__ write_b,
    const uint_t* __restrict__ A2, float* __restrict__ g_headp) {
  const int blk = blockIdx.x, tid = threadIdx.x;
  const int lane = tid & 63, u = tid >> 6;
  const int r = blk * 8 + u;
  __shared__ uint_t s_tile[64 * 64];
  __shared__ float s_tr[8 * 65];
  const int hbase = 160 + 256 * wslot;
  float acc = 0.f;
  const uint_t* wrow = W2h + (size_t)r * 256;
  for (int c = 0; c < 4; ++c) {
    for (int i = tid; i < 64 * 64; i += 512) {
      int kk = i >> 6, bb = i & 63;
      s_tile[i] = A2[(size_t)(hbase + c * 64 + kk) * 64 + bb];
    }
    __syncthreads();
    #pragma unroll 4
    for (int kk = 0; kk < 64; ++kk) {
      uint_t ua = s_tile[kk * 64 + lane];
      uint_t w = wrow[c * 64 + kk];
      acc += bflo(w) * bflo(ua) + bfhi(w) * bfhi(ua);
    }
    __syncthreads();
  }
  acc += (r < 280) ? read_b[r] : write_b[r - 280];
  s_tr[u * 65 + lane] = acc;
  __syncthreads();
  if (tid < 128) {
    int bb = tid & 63, half = tid >> 6;
    float4 v;
    v.x = s_tr[(half * 4 + 0) * 65 + bb];
    v.y = s_tr[(half * 4 + 1) * 65 + bb];
    v.z = s_tr[(half * 4 + 2) * 65 + bb];
    v.w = s_tr[(half * 4 + 3) * 65 + bb];
    *(float4*)(g_headp + (size_t)bb * 1088 + blk * 8 + half * 4) = v;
  }
}

// ============ K3: per-batch memory phase — mem LDS-resident ============
// Dynamic LDS: 1024 rows x 32 uints, rotation-swizzled: slot(row,c) = (c+row)&31.
// Conflict-free for row-major dot reads AND column-major einsum/erase.
__global__ __launch_bounds__(1024) void k3_mem(
    int t, const float* __restrict__ x, const float* __restrict__ g_headp,
    ushort_t* __restrict__ g_mem, uint_t* __restrict__ A2,
    float* __restrict__ g_ws) {
  const int b = blockIdx.x, tid = threadIdx.x;
  const int lane = tid & 63, wave = tid >> 6;
  extern __shared__ uint_t s_mem[];            // 131072 B
  __shared__ alignas(16) float s_wgA[1024];    // wgR, then wR final
  __shared__ alignas(16) float s_wgB[1024];    // wgW, then wW final
  __shared__ alignas(16) float s_part[1024];
  __shared__ alignas(16) float s_reads[RR * VV];
  __shared__ alignas(16) float s_or[72];
  __shared__ alignas(16) float s_ow[200];
  __shared__ alignas(16) float s_e[VV];
  __shared__ alignas(16) float s_a[VV];
  __shared__ float s_redR[16];
  __shared__ float s_redW[16];
  uint_t* m32 = (uint_t*)(g_mem + (size_t)b * (NN * VV));
  const float* hp = g_headp + (size_t)b * 1088;

  for (int hd = 0; hd < RR; ++hd) {
    if (tid < 70) s_or[tid] = hp[hd * 70 + tid];
    else if (tid >= 128 && tid < 326) s_ow[tid - 128] = hp[280 + hd * 198 + (tid - 128)];
    __syncthreads();                              // S0
    if (tid < VV) { s_e[tid] = sigf(s_ow[70 + tid]); s_a[tid] = s_ow[134 + tid]; }

    float wprevR = g_ws[(size_t)(b * 8 + 2 * hd) * 1024 + tid];
    float wprevW = g_ws[(size_t)(b * 8 + 2 * hd + 1) * 1024 + tid];

    // ---- dot pass over own row (tid): dual keys + |row|^2 ----
    float dotR = 0.f, dotW = 0.f, kkR = 0.f, kkW = 0.f, nrm2 = 0.f;
    if (hd == 0) {
      // stream from EA (coalesced uint4) + deposit rotated into LDS
      const uint4* rowp = (const uint4*)(m32 + (size_t)tid * 32);
      const float4* orf = (const float4*)s_or;
      const float4* owf = (const float4*)s_ow;
      #pragma unroll
      for (int p = 0; p < 8; ++p) {
        uint4 m = rowp[p];
        s_mem[tid * 32 + ((4 * p + 0 + tid) & 31)] = m.x;
        s_mem[tid * 32 + ((4 * p + 1 + tid) & 31)] = m.y;
        s_mem[tid * 32 + ((4 * p + 2 + tid) & 31)] = m.z;
        s_mem[tid * 32 + ((4 * p + 3 + tid) & 31)] = m.w;
        float4 ka = orf[2 * p], kb = orf[2 * p + 1];
        float4 wa = owf[2 * p], wb = owf[2 * p + 1];
        kkR += dot4f(ka, ka) + dot4f(kb, kb);
        kkW += dot4f(wa, wa) + dot4f(wb, wb);
        float m0 = bflo(m.x), m1 = bfhi(m.x), m2 = bflo(m.y), m3 = bfhi(m.y);
        float m4 = bflo(m.z), m5 = bfhi(m.z), m6 = bflo(m.w), m7 = bfhi(m.w);
        nrm2 += m0 * m0 + m1 * m1 + m2 * m2 + m3 * m3 + m4 * m4 + m5 * m5 + m6 * m6 + m7 * m7;
        dotR += m0 * ka.x + m1 * ka.y + m2 * ka.z + m3 * ka.w +
                m4 * kb.x + m5 * kb.y + m6 * kb.z + m7 * kb.w;
        dotW += m0 * wa.x + m1 * wa.y + m2 * wa.z + m3 * wa.w +
                m4 * wb.x + m5 * wb.y + m6 * wb.z + m7 * wb.w;
      }
    } else {
      #pragma unroll 8
      for (int c = 0; c < 32; ++c) {
        uint_t u = s_mem[tid * 32 + ((c + tid) & 31)];
        float v0 = bflo(u), v1 = bfhi(u);
        float kR0 = s_or[2 * c], kR1 = s_or[2 * c + 1];
        float kW0 = s_ow[2 * c], kW1 = s_ow[2 * c + 1];
        nrm2 += v0 * v0 + v1 * v1;
        dotR += v0 * kR0 + v1 * kR1;
        dotW += v0 * kW0 + v1 * kW1;
        kkR += kR0 * kR0 + kR1 * kR1;
        kkW += kW0 * kW0 + kW1 * kW1;
      }
    }
    float na = fmaxf(sqrtf(nrm2), 1e-8f);

    // ---- dual softmax chain ----
    float nbR = fmaxf(sqrtf(kkR), 1e-8f), nbW = fmaxf(sqrtf(kkW), 1e-8f);
    float betaR = splus(s_or[64]), betaW = splus(s_ow[64]);
    float gR = sigf(s_or[65]), gW = sigf(s_ow[65]);
    float r0 = s_or[66], r1 = s_or[67], r2 = s_or[68];
    float q0 = s_ow[66], q1 = s_ow[67], q2 = s_ow[68];
    float mxR = fmaxf(r0, fmaxf(r1, r2)), mxW = fmaxf(q0, fmaxf(q1, q2));
    float eR0 = __expf(r0 - mxR), eR1 = __expf(r1 - mxR), eR2 = __expf(r2 - mxR);
    float eW0 = __expf(q0 - mxW), eW1 = __expf(q1 - mxW), eW2 = __expf(q2 - mxW);
    float siR = 1.0f / (eR0 + eR1 + eR2), siW = 1.0f / (eW0 + eW1 + eW2);
    float gamR = 1.0f + splus(s_or[69]), gamW = 1.0f + splus(s_ow[69]);
    float eeR = __expf(betaR * dotR / (na * nbR));   // |z|<=beta: no max-sub
    float eeW = __expf(betaW * dotW / (na * nbW));
    float vR = eeR, vW = eeW;
    #pragma unroll
    for (int o = 32; o; o >>= 1) { vR += __shfl_xor(vR, o); vW += __shfl_xor(vW, o); }
    if (lane == 0) { s_redR[wave] = vR; s_redW[wave] = vW; }
    __syncthreads();                              // S1
    float SR = 0.f, SW = 0.f;
    #pragma unroll
    for (int w = 0; w < 16; ++w) { SR += s_redR[w]; SW += s_redW[w]; }
    float wgR = gR * (eeR / SR) + (1.0f - gR) * wprevR;
    float wgW = gW * (eeW / SW) + (1.0f - gW) * wprevW;
    s_wgA[tid] = wgR;
    s_wgB[tid] = wgW;
    __syncthreads();                              // S2
    int tm = (tid + 1023) & 1023, tp = (tid + 1) & 1023;
    float wsnR = (eR0 * siR) * s_wgA[tm] + (eR1 * siR) * s_wgA[tid] + (eR2 * siR) * s_wgA[tp];
    float wsnW = (eW0 * siW) * s_wgB[tm] + (eW1 * siW) * s_wgB[tid] + (eW2 * siW) * s_wgB[tp];
    float wpR = __expf(gamR * __logf(wsnR));
    float wpW = __expf(gamW * __logf(wsnW));
    vR = wpR; vW = wpW;
    #pragma unroll
    for (int o = 32; o; o >>= 1) { vR += __shfl_xor(vR, o); vW += __shfl_xor(vW, o); }
    if (lane == 0) { s_redR[wave] = vR; s_redW[wave] = vW; }
    __syncthreads();                              // S3 (all shift reads done)
    float ZR = 0.f, ZW = 0.f;
    #pragma unroll
    for (int w = 0; w < 16; ++w) { ZR += s_redR[w]; ZW += s_redW[w]; }
    float wRf = wpR / (ZR + 1e-16f);
    float wWf = wpW / (ZW + 1e-16f);
    s_wgA[tid] = wRf;
    s_wgB[tid] = wWf;
    g_ws[(size_t)(b * 8 + 2 * hd) * 1024 + tid] = wRf;
    g_ws[(size_t)(b * 8 + 2 * hd + 1) * 1024 + tid] = wWf;
    __syncthreads();                              // S4: wR/wW visible

    // ---- fused einsum + erase in LDS (head 3 erase -> EA) ----
    {
      const int cp = lane & 31, half = lane >> 5;
      const float e0 = s_e[2 * cp], e1 = s_e[2 * cp + 1];
      const float a0 = s_a[2 * cp], a1 = s_a[2 * cp + 1];
      const int rbase = wave * 64 + half;
      float acc0 = 0.f, acc1 = 0.f;
      #pragma unroll 8
      for (int q = 0; q < 32; ++q) {
        int row = rbase + 2 * q;
        int addr = row * 32 + ((cp + row) & 31);
        uint_t uu = s_mem[addr];
        float wRn = s_wgA[row];
        float wWn = s_wgB[row];
        float v0 = bflo(uu), v1 = bfhi(uu);
        acc0 += wRn * v0; acc1 += wRn * v1;
        float n0 = v0 * (1.f - wWn * e0) + wWn * a0;
        float n1 = v1 * (1.f - wWn * e1) + wWn * a1;
        uint_t nu = packbf(n0, n1);
        if (hd < 3) s_mem[addr] = nu;
        else        m32[(size_t)row * 32 + cp] = nu;   // final mem -> EA, coalesced
      }
      acc0 += __shfl_xor(acc0, 32);
      acc1 += __shfl_xor(acc1, 32);
      if (half == 0) *(float2*)(s_part + wave * 64 + 2 * cp) = make_float2(acc0, acc1);
    }
    __syncthreads();                              // S5
    if (tid < VV) {
      float s = 0.f;
      #pragma unroll
      for (int w2 = 0; w2 < 16; ++w2) s += s_part[w2 * 64 + tid];
      s_reads[hd * VV + tid] = s;
    }
  } // hd
  __syncthreads();

  // publish reads_t and x_{t+1} into A (bf16 pairs)
  if (tid < 128)
    A2[(size_t)(32 + tid) * 64 + b] = packbf(s_reads[2 * tid], s_reads[2 * tid + 1]);
  if (tid < 32 && t + 1 < TT) {
    float v0 = x[((size_t)b * TT + t + 1) * DD + 2 * tid];
    float v1 = x[((size_t)b * TT + t + 1) * DD + 2 * tid + 1];
    A2[(size_t)tid * 64 + b] = packbf(v0, v1);
  }
}

extern "C" void kernel_launch(void* const* d_in, const int* in_sizes, int n_in,
                              void* d_out, int out_size, void* d_ws, size_t ws_size,
                              hipStream_t stream) {
  char* ws = (char*)d_ws;
  ushort_t* g_mem = (ushort_t*)ws;                 // 8,388,608
  uint_t* g_A2    = (uint_t*)(ws + 8388608);       //   172,032
  float* g_c      = (float*)(ws + 8560640);        //   131,072
  float* g_ws     = (float*)(ws + 8691712);        // 2,097,152
  float* g_headp  = (float*)(ws + 10788864);       //   278,528
  uint_t* W2g     = (uint_t*)(ws + 11067392);      // 3,514,368
  uint_t* W2h     = (uint_t*)(ws + 14581760);      // 1,097,728
  float* gbias    = (float*)(ws + 15679488);       //     8,192   (~15.7 MB)

  const float* x        = (const float*)d_in[0];
  const float* mem_bias = (const float*)d_in[1];
  const float* h_bias   = (const float*)d_in[2];
  const float* c_bias   = (const float*)d_in[3];
  const float* W_ih     = (const float*)d_in[4];
  const float* W_hh     = (const float*)d_in[5];
  const float* b_ih     = (const float*)d_in[6];
  const float* b_hh     = (const float*)d_in[7];
  const float* read_W   = (const float*)d_in[8];
  const float* read_b   = (const float*)d_in[9];
  const float* write_W  = (const float*)d_in[10];
  const float* write_b  = (const float*)d_in[11];
  const float* read_init= (const float*)d_in[12];
  const float* out_W    = (const float*)d_in[13];
  const float* out_b    = (const float*)d_in[14];
  float* out = (float*)d_out;

  bias_kernel<<<8, 256, 0, stream>>>(b_ih, b_hh, gbias);
  build_gw<<<3432, 256, 0, stream>>>(W_ih, W_hh, out_W, W2g);
  build_hw<<<1072, 256, 0, stream>>>(read_W, write_W, W2h);
  k0_init<<<64, 1024, 0, stream>>>(x, mem_bias, h_bias, c_bias, read_init,
                                   g_mem, g_A2, g_c, g_ws);
  for (int t = 0; t < TT; ++t) {
    k1_gates<<<72, 512, 0, stream>>>(t, 64, t & 1, W2g, gbias, g_A2, g_c, out_b, out);
    k2_heads<<<134, 512, 0, stream>>>((t + 1) & 1, W2h, read_b, write_b, g_A2, g_headp);
    k3_mem<<<64, 1024, 131072, stream>>>(t, x, g_headp, g_mem, g_A2, g_ws);
  }
  // final out row batch: out(t=31) from h_31 (slot 0) + reads_31
  k1_gates<<<8, 512, 0, stream>>>(TT, 0, 0, W2g, gbias, g_A2, g_c, out_b, out);
}